// Round 8
// baseline (228.128 us; speedup 1.0000x reference)
//
#include <hip/hip_runtime.h>
#include <float.h>

#define S_LEN 4096
#define E_DIM 1152
#define NH    16
#define HD    72
#define HD2   36
#define NQKV  3456

typedef __attribute__((ext_vector_type(4))) float f32x4;
typedef __attribute__((ext_vector_type(2))) __fp16 fp16v2;
typedef __attribute__((ext_vector_type(8))) _Float16 f16x8;

__device__ __forceinline__ unsigned short f2h(float f) {
    union { _Float16 h; unsigned short u; } c;
    c.h = (_Float16)f;
    return c.u;
}
__device__ __forceinline__ unsigned pack2h(float a, float b) {
    union { fp16v2 v; unsigned u; } c;
    c.v = __builtin_amdgcn_cvt_pkrtz(a, b);
    return c.u;
}

// async 16B global->LDS (lane i deposits at wave-uniform base + 16*lane)
__device__ __forceinline__ void gload_lds16(const unsigned short* g, unsigned short* l) {
    __builtin_amdgcn_global_load_lds(
        (const __attribute__((address_space(1))) unsigned int*)g,
        (__attribute__((address_space(3))) unsigned int*)l, 16, 0, 0);
}

// ======== pack: fp32 -> fp16 ========
__global__ __launch_bounds__(256)
void pack_f16(const float* __restrict__ hs, const float* __restrict__ wq,
              const float* __restrict__ wk, const float* __restrict__ wv,
              const float* __restrict__ wo,
              unsigned short* __restrict__ hs_h, unsigned short* __restrict__ wqkv_h,
              unsigned short* __restrict__ wo_h)
{
    const float* src; unsigned short* dst; int n4;
    const int WSZ = E_DIM * E_DIM;
    switch (blockIdx.z) {
        case 0: src = hs; dst = hs_h;             n4 = S_LEN * E_DIM / 4; break;
        case 1: src = wq; dst = wqkv_h;           n4 = WSZ / 4; break;
        case 2: src = wk; dst = wqkv_h + WSZ;     n4 = WSZ / 4; break;
        case 3: src = wv; dst = wqkv_h + 2 * WSZ; n4 = WSZ / 4; break;
        default: src = wo; dst = wo_h;            n4 = WSZ / 4; break;
    }
    for (int i = blockIdx.x * 256 + threadIdx.x; i < n4; i += gridDim.x * 256) {
        f32x4 x = ((const f32x4*)src)[i];
        uint2 hv;
        hv.x = pack2h(x[0], x[1]);
        hv.y = pack2h(x[2], x[3]);
        ((uint2*)dst)[i] = hv;
    }
}

// ======== fp16 MFMA GEMM: C = A@W^T + b, M=4096 N=3456 K=1152, BK=64 ========
__global__ __launch_bounds__(256, 4)
void gemm_qkv_f16(const unsigned short* __restrict__ Ah, const unsigned short* __restrict__ Wh,
                  const float* __restrict__ bq, const float* __restrict__ bk,
                  const float* __restrict__ bv,
                  float* __restrict__ oq, float* __restrict__ ok, float* __restrict__ ov)
{
    __shared__ unsigned short sA[128 * 64];
    __shared__ unsigned short sB[128 * 64];
    const int tid  = threadIdx.x;
    const int w    = tid >> 6, lane = tid & 63;
    const int quad = lane >> 4, m = lane & 15;
    const int wr   = w & 1,  wc = w >> 1;

    const int bid = blockIdx.x;
    const int lin = (bid & 7) * 108 + (bid >> 3);
    const int n_t = lin >> 5;
    const int m_t = lin & 31;
    const int m0  = m_t * 128;
    const int n0  = n_t * 128;

    const int srow = lane >> 3;
    const int skc  = (lane & 7) ^ srow;

    f32x4 acc[4][4];
    #pragma unroll
    for (int i = 0; i < 4; ++i)
        #pragma unroll
        for (int j = 0; j < 4; ++j) acc[i][j] = (f32x4){0.f, 0.f, 0.f, 0.f};

    const int rm7 = m & 7;

    for (int k0 = 0; k0 < E_DIM; k0 += 64) {
        #pragma unroll
        for (int c = 0; c < 4; ++c) {
            int r = 32 * w + 8 * c + srow;
            gload_lds16(Ah + (size_t)(m0 + r) * E_DIM + k0 + skc * 8, &sA[(32 * w + 8 * c) * 64]);
            gload_lds16(Wh + (size_t)(n0 + r) * E_DIM + k0 + skc * 8, &sB[(32 * w + 8 * c) * 64]);
        }
        __syncthreads();

        #pragma unroll
        for (int k3 = 0; k3 < 2; ++k3) {
            f16x8 ah[4], bh[4];
            #pragma unroll
            for (int t = 0; t < 4; ++t) {
                int pc = ((k3 << 2) + quad) ^ rm7;
                ah[t] = *(const f16x8*)&sA[(64 * wr + 16 * t + m) * 64 + pc * 8];
                bh[t] = *(const f16x8*)&sB[(64 * wc + 16 * t + m) * 64 + pc * 8];
            }
            #pragma unroll
            for (int rt = 0; rt < 4; ++rt)
                #pragma unroll
                for (int ct = 0; ct < 4; ++ct)
                    acc[rt][ct] = __builtin_amdgcn_mfma_f32_16x16x32_f16(ah[rt], bh[ct], acc[rt][ct], 0, 0, 0);
        }
        __syncthreads();
    }

    const int which = n0 / E_DIM;
    const int n0l = n0 - which * E_DIM;
    const float* bp = (which == 0) ? bq : (which == 1) ? bk : bv;
    float* Cp       = (which == 0) ? oq : (which == 1) ? ok : ov;
    #pragma unroll
    for (int ct = 0; ct < 4; ++ct) {
        int col = n0l + 64 * wc + 16 * ct + m;
        float bias = bp[col];
        #pragma unroll
        for (int rt = 0; rt < 4; ++rt)
            #pragma unroll
            for (int reg = 0; reg < 4; ++reg) {
                int row = m0 + 64 * wr + 16 * rt + 4 * quad + reg;
                Cp[(size_t)row * E_DIM + col] = acc[rt][ct][reg] + bias;
            }
    }
}

// ======== fp16 MFMA GEMM: out = A@W^T + b. 64x128 tile, BK=64 ========
__global__ __launch_bounds__(256, 4)
void gemm_out_f16(const unsigned short* __restrict__ Ah, const unsigned short* __restrict__ Wh,
                  const float* __restrict__ bo, float* __restrict__ Cp)
{
    __shared__ unsigned short sA[64 * 64];
    __shared__ unsigned short sB[128 * 64];
    const int tid  = threadIdx.x;
    const int w    = tid >> 6, lane = tid & 63;
    const int quad = lane >> 4, m = lane & 15;
    const int m0   = blockIdx.y * 64;
    const int n0   = blockIdx.x * 128;

    const int srow = lane >> 3;
    const int skc  = (lane & 7) ^ srow;

    f32x4 acc[4][2];
    #pragma unroll
    for (int i = 0; i < 4; ++i)
        #pragma unroll
        for (int j = 0; j < 2; ++j) acc[i][j] = (f32x4){0.f, 0.f, 0.f, 0.f};

    const int rm7 = m & 7;

    for (int k0 = 0; k0 < E_DIM; k0 += 64) {
        #pragma unroll
        for (int c = 0; c < 2; ++c) {
            int r = 16 * w + 8 * c + srow;
            gload_lds16(Ah + (size_t)(m0 + r) * E_DIM + k0 + skc * 8, &sA[(16 * w + 8 * c) * 64]);
        }
        #pragma unroll
        for (int c = 0; c < 4; ++c) {
            int r = 32 * w + 8 * c + srow;
            gload_lds16(Wh + (size_t)(n0 + r) * E_DIM + k0 + skc * 8, &sB[(32 * w + 8 * c) * 64]);
        }
        __syncthreads();
        #pragma unroll
        for (int k3 = 0; k3 < 2; ++k3) {
            f16x8 ah[4], bh[2];
            int pc = ((k3 << 2) + quad) ^ rm7;
            #pragma unroll
            for (int t = 0; t < 4; ++t)
                ah[t] = *(const f16x8*)&sA[(16 * t + m) * 64 + pc * 8];
            #pragma unroll
            for (int ct = 0; ct < 2; ++ct)
                bh[ct] = *(const f16x8*)&sB[(32 * w + 16 * ct + m) * 64 + pc * 8];
            #pragma unroll
            for (int rt = 0; rt < 4; ++rt)
                #pragma unroll
                for (int ct = 0; ct < 2; ++ct)
                    acc[rt][ct] = __builtin_amdgcn_mfma_f32_16x16x32_f16(ah[rt], bh[ct], acc[rt][ct], 0, 0, 0);
        }
        __syncthreads();
    }

    #pragma unroll
    for (int ct = 0; ct < 2; ++ct) {
        int col = n0 + 32 * w + 16 * ct + m;
        float bias = bo[col];
        #pragma unroll
        for (int rt = 0; rt < 4; ++rt)
            #pragma unroll
            for (int reg = 0; reg < 4; ++reg) {
                int row = m0 + 16 * rt + 4 * quad + reg;
                Cp[(size_t)row * E_DIM + col] = acc[rt][ct][reg] + bias;
            }
    }
}

// ==== rope+pack q,k -> [h][S][72] fp16 (z=0,1); v transpose -> [h][72][S] (z=2) ====
__global__ __launch_bounds__(256)
void rope_v_pack(const float* __restrict__ qf, const float* __restrict__ kf,
                 const float* __restrict__ vf,
                 const float* __restrict__ cosb, const float* __restrict__ sinb,
                 unsigned short* __restrict__ qb, unsigned short* __restrict__ kb,
                 unsigned short* __restrict__ vt)
{
    __shared__ unsigned short tile[HD][72];
    const int h  = blockIdx.y;
    const int s0 = blockIdx.x * 64;
    const int z  = blockIdx.z;
    if (z < 2) {
        const float* x = (z == 0) ? qf : kf;
        unsigned short* ob = (z == 0) ? qb : kb;
        for (int task = threadIdx.x; task < 64 * 9; task += 256) {
            int sl = task / 9, c = task % 9;
            int s = s0 + sl;
            int d0 = c << 2;
            const float* xr = x + (size_t)s * E_DIM + h * HD;
            f32x4 a  = *(const f32x4*)(xr + d0);
            f32x4 b  = *(const f32x4*)(xr + d0 + HD2);
            f32x4 c1 = *(const f32x4*)(cosb + (size_t)s * HD + d0);
            f32x4 s1 = *(const f32x4*)(sinb + (size_t)s * HD + d0);
            f32x4 c2 = *(const f32x4*)(cosb + (size_t)s * HD + d0 + HD2);
            f32x4 s2 = *(const f32x4*)(sinb + (size_t)s * HD + d0 + HD2);
            f32x4 r1 = a * c1 - b * s1;
            f32x4 r2 = b * c2 + a * s2;
            unsigned short* orow = ob + ((size_t)h * S_LEN + s) * HD;
            uint2 u1, u2;
            u1.x = pack2h(r1[0], r1[1]); u1.y = pack2h(r1[2], r1[3]);
            u2.x = pack2h(r2[0], r2[1]); u2.y = pack2h(r2[2], r2[3]);
            *(uint2*)(orow + d0)       = u1;
            *(uint2*)(orow + d0 + HD2) = u2;
        }
    } else {
        for (int task = threadIdx.x; task < 64 * 18; task += 256) {
            int r = task / 18, c = task % 18;
            f32x4 x = *(const f32x4*)(vf + (size_t)(s0 + r) * E_DIM + h * HD + (c << 2));
            tile[(c << 2) + 0][r] = f2h(x[0]);
            tile[(c << 2) + 1][r] = f2h(x[1]);
            tile[(c << 2) + 2][r] = f2h(x[2]);
            tile[(c << 2) + 3][r] = f2h(x[3]);
        }
        __syncthreads();
        for (int task = threadIdx.x; task < HD * 8; task += 256) {
            int d = task / 8, cc = task % 8;
            uint4 val = *(const uint4*)&tile[d][cc << 3];
            *(uint4*)(vt + ((size_t)h * HD + d) * S_LEN + s0 + (cc << 3)) = val;
        }
    }
}

// ==== MFMA flash attention: K·Q^T swap + shuffle P-transform, no P LDS ====
// S^T in C layout: lane(m,quad) holds S[qrow=16w+m][key=16ct+4quad+reg].
// PV A-frag built in-register via shuffles (no ss_s round-trip).
__global__ __launch_bounds__(256, 4)
void attn_f16(const unsigned short* __restrict__ qb, const unsigned short* __restrict__ kb,
              const unsigned short* __restrict__ vt, const int* __restrict__ cu,
              int nseg, unsigned short* __restrict__ out)
{
    __shared__ unsigned short ks_s[64][72];
    __shared__ unsigned short vs_s[80][72];

    const int tid  = threadIdx.x;
    const int w    = tid >> 6;
    const int lane = tid & 63;
    const int quad = lane >> 4;
    const int m    = lane & 15;
    const int h    = blockIdx.y;
    const int qb0  = blockIdx.x * 64;
    const float scale = 0.11785113019775793f;   // 72^-0.5

    {
        uint4 zz = make_uint4(0u, 0u, 0u, 0u);
        if (tid < 72) {
            int r = 72 + tid / 9, c = tid % 9;
            *(uint4*)&vs_s[r][c << 3] = zz;
        }
    }

    // per-lane Q-row bounds (this lane's q-row in S^T cols = 16w+m)
    const int qrow = qb0 + 16 * w + m;
    int st = 0;
    for (int i = 1; i < nseg; ++i) if (cu[i] <= qrow) st = i;
    const int rs = cu[st], re = cu[st + 1];

    int st0 = 0, st1 = 0;
    for (int i = 1; i < nseg; ++i) {
        if (cu[i] <= qb0) st0 = i;
        if (cu[i] <= qb0 + 63) st1 = i;
    }
    const int kstart = cu[st0];
    const int kend   = cu[st1 + 1];

    // Q fragments (B-operand): B[n=m][k=quad*8+j]
    f16x8 qfr[3];
    {
        const unsigned short* qrp = qb + ((size_t)h * S_LEN + qrow) * HD;
        #pragma unroll
        for (int k3 = 0; k3 < 3; ++k3) {
            bool pad = (k3 == 2) && (quad != 0);
            int off = pad ? 0 : (k3 * 32 + quad * 8);
            f16x8 val = *(const f16x8*)(qrp + off);
            f16x8 z = {0, 0, 0, 0, 0, 0, 0, 0};
            qfr[k3] = pad ? z : val;
        }
    }

    f32x4 acc_o[5];
    #pragma unroll
    for (int i = 0; i < 5; ++i) acc_o[i] = (f32x4){0.f, 0.f, 0.f, 0.f};
    float l_s = 0.f;

    const int srcA = 32 * (quad & 1) + m;
    const bool sel = (quad >> 1) != 0;

    for (int kb_i = kstart; kb_i < kend; kb_i += 64) {
        __syncthreads();
        // stage K tile (pre-roped fp16)
        for (int slot = tid; slot < 64 * 9; slot += 256) {
            int r = slot / 9, c = slot % 9;
            int krow = kb_i + r; if (krow >= kend) krow = kend - 1;
            uint4 val = *(const uint4*)(kb + ((size_t)h * S_LEN + krow) * HD + (c << 3));
            *(uint4*)&ks_s[r][c << 3] = val;
        }
        // stage V tile (fp16 dim-major)
        for (int slot = tid; slot < 72 * 8; slot += 256) {
            int d = slot / 8, c = slot % 8;
            int kk0 = kb_i + (c << 3);
            if (kk0 > S_LEN - 8) kk0 = S_LEN - 8;
            uint4 val = *(const uint4*)(vt + ((size_t)h * HD + d) * S_LEN + kk0);
            *(uint4*)&vs_s[d][c << 3] = val;
        }
        __syncthreads();

        // S^T = K Q^T (A = K rows=keys, B = Q cols=qrows)
        f32x4 sacc[4];
        #pragma unroll
        for (int ct = 0; ct < 4; ++ct) sacc[ct] = (f32x4){0.f, 0.f, 0.f, 0.f};
        #pragma unroll
        for (int ct = 0; ct < 4; ++ct) {
            const unsigned short* krow = &ks_s[16 * ct + m][0];
            #pragma unroll
            for (int k3 = 0; k3 < 3; ++k3) {
                bool pad = (k3 == 2) && (quad != 0);
                int off = pad ? 0 : (k3 * 32 + quad * 8);
                f16x8 kfr = *(const f16x8*)(krow + off);
                f16x8 z = {0, 0, 0, 0, 0, 0, 0, 0};
                kfr = pad ? z : kfr;
                sacc[ct] = __builtin_amdgcn_mfma_f32_16x16x32_f16(kfr, qfr[k3], sacc[ct], 0, 0, 0);
            }
        }

        // exp + mask; pack pairs (reg01, reg23) per ct
        unsigned pk[4][2];
        #pragma unroll
        for (int ct = 0; ct < 4; ++ct) {
            float p[4];
            #pragma unroll
            for (int reg = 0; reg < 4; ++reg) {
                int key = kb_i + 16 * ct + 4 * quad + reg;
                bool valid = (key >= rs) && (key < re);
                p[reg] = valid ? __expf(sacc[ct][reg] * scale) : 0.f;
                l_s += p[reg];
            }
            pk[ct][0] = pack2h(p[0], p[1]);
            pk[ct][1] = pack2h(p[2], p[3]);
        }

        // build P A-frags: chunk c keys 32c..32c+31; receiver (m,q) pulls
        // pk[2c+(q>>1)][r] from lanes srcA (j0..3) and srcA+16 (j4..7)
        f16x8 pf[2];
        #pragma unroll
        for (int c = 0; c < 2; ++c) {
            union { unsigned d[4]; f16x8 v; } fb;
            #pragma unroll
            for (int r = 0; r < 2; ++r) {
                int x0 = __shfl((int)pk[2 * c][r],     srcA);
                int x1 = __shfl((int)pk[2 * c + 1][r], srcA);
                fb.d[r] = (unsigned)(sel ? x1 : x0);
                int y0 = __shfl((int)pk[2 * c][r],     srcA + 16);
                int y1 = __shfl((int)pk[2 * c + 1][r], srcA + 16);
                fb.d[2 + r] = (unsigned)(sel ? y1 : y0);
            }
            pf[c] = fb.v;
        }

        // O += P V  (A = P rows=qrows, B = V^T cols=dims)
        #pragma unroll
        for (int ct2 = 0; ct2 < 5; ++ct2) {
            const unsigned short* vrow = &vs_s[16 * ct2 + m][0];
            f16x8 vf0 = *(const f16x8*)(vrow + quad * 8);
            f16x8 vf1 = *(const f16x8*)(vrow + 32 + quad * 8);
            acc_o[ct2] = __builtin_amdgcn_mfma_f32_16x16x32_f16(pf[0], vf0, acc_o[ct2], 0, 0, 0);
            acc_o[ct2] = __builtin_amdgcn_mfma_f32_16x16x32_f16(pf[1], vf1, acc_o[ct2], 0, 0, 0);
        }
    }

    // l: reduce across quads (same m), then broadcast to C-layout rows
    l_s += __shfl_xor(l_s, 16);
    l_s += __shfl_xor(l_s, 32);

    #pragma unroll
    for (int reg = 0; reg < 4; ++reg) {
        float lr = __shfl(l_s, 4 * quad + reg);
        float linv = (lr > 0.f) ? 1.f / lr : 0.f;
        int row = qb0 + 16 * w + 4 * quad + reg;
        unsigned short* orow = out + (size_t)row * E_DIM + h * HD;
        #pragma unroll
        for (int ct2 = 0; ct2 < 5; ++ct2) {
            int col = 16 * ct2 + m;
            if (col < HD) orow[col] = f2h(acc_o[ct2][reg] * linv);
        }
    }
}

// ================= launch =================
extern "C" void kernel_launch(void* const* d_in, const int* in_sizes, int n_in,
                              void* d_out, int out_size, void* d_ws, size_t ws_size,
                              hipStream_t stream)
{
    const float* hs   = (const float*)d_in[0];
    const int*   cu   = (const int*)d_in[1];
    const float* cosb = (const float*)d_in[2];
    const float* sinb = (const float*)d_in[3];
    const float* Wq   = (const float*)d_in[4];
    const float* bq   = (const float*)d_in[5];
    const float* Wk   = (const float*)d_in[6];
    const float* bk   = (const float*)d_in[7];
    const float* Wv   = (const float*)d_in[8];
    const float* bv   = (const float*)d_in[9];
    const float* Wo   = (const float*)d_in[10];
    const float* bo   = (const float*)d_in[11];
    float* outp = (float*)d_out;

    const size_t mat = (size_t)S_LEN * E_DIM;
    float* qf = (float*)d_ws;
    float* kf = qf + mat;
    float* vf = kf + mat;
    unsigned short* hs_h   = (unsigned short*)(vf + mat);
    unsigned short* wqkv_h = hs_h + mat;
    unsigned short* wo_h   = wqkv_h + (size_t)NQKV * E_DIM;
    unsigned short* vtb    = wo_h + (size_t)E_DIM * E_DIM;
    unsigned short* kbb    = vtb + mat;
    unsigned short* qbb    = hs_h;                  // overlay: hs_h free after gemm_qkv
    unsigned short* attn_h = (unsigned short*)qf;   // overlay: qf free after rope

    const int nseg = in_sizes[1] - 1;

    dim3 gpack(512, 1, 5);
    pack_f16<<<gpack, 256, 0, stream>>>(hs, Wq, Wk, Wv, Wo, hs_h, wqkv_h, wo_h);

    gemm_qkv_f16<<<dim3(864), 256, 0, stream>>>(hs_h, wqkv_h, bq, bk, bv, qf, kf, vf);

    dim3 grv(S_LEN / 64, NH, 3);
    rope_v_pack<<<grv, 256, 0, stream>>>(qf, kf, vf, cosb, sinb, qbb, kbb, vtb);

    dim3 gattn(S_LEN / 64, NH, 1);
    attn_f16<<<gattn, 256, 0, stream>>>(qbb, kbb, vtb, cu, nseg, attn_h);

    dim3 gout(E_DIM / 128, S_LEN / 64, 1);
    gemm_out_f16<<<gout, 256, 0, stream>>>(attn_h, wo_h, bo, outp);
}